// Round 8
// baseline (495.501 us; speedup 1.0000x reference)
//
#include <hip/hip_runtime.h>
#include <math.h>

#define BATCH 2
#define S_LEN 2048
#define DMODEL 1024
#define NH 16
#define HDIM 64
#define SCALE 0.125f
// SCALE * log2(e): exp(l*SCALE) == exp2(l*KC)
#define KC 0.18033688011112042f

typedef short bf16x8 __attribute__((ext_vector_type(8)));
typedef _Float16 f16x8 __attribute__((ext_vector_type(8)));
typedef float f32x4 __attribute__((ext_vector_type(4)));
typedef unsigned short u16;
#define MFMA(a, b, c) __builtin_amdgcn_mfma_f32_16x16x32_bf16(a, b, c, 0, 0, 0)
#define MFMA16(a, b, c) __builtin_amdgcn_mfma_f32_16x16x32_f16(a, b, c, 0, 0, 0)

static __device__ __forceinline__ float bf2f(u16 u) {
  return __uint_as_float(((unsigned int)u) << 16);
}
static __device__ __forceinline__ u16 f2h_bits(float a) {
  _Float16 h = (_Float16)a;
  return *(u16*)&h;
}

// round-to-nearest-even split: a ~= hi + lo, both bf16
static __device__ __forceinline__ void split_bf16(float a, u16& hi, u16& lo) {
  unsigned int u = __float_as_uint(a);
  unsigned int r = (u + 0x7fffu + ((u >> 16) & 1u)) >> 16;
  hi = (u16)r;
  float res = a - __uint_as_float(r << 16);
  unsigned int u2 = __float_as_uint(res);
  lo = (u16)((u2 + 0x7fffu + ((u2 >> 16) & 1u)) >> 16);
}

static __device__ __forceinline__ float qredsum(float v) {
#pragma unroll
  for (int off = 8; off >= 1; off >>= 1) v += __shfl_xor(v, off, 16);
  return v;
}

// async global->LDS, 16B per lane; LDS dest = wave-uniform base + lane*16
static __device__ __forceinline__ void async_ld16(u16* lds, const u16* g) {
  __builtin_amdgcn_global_load_lds(
      (const __attribute__((address_space(1))) void*)(const void*)g,
      (__attribute__((address_space(3))) void*)(void*)lds, 16, 0, 0);
}

// load 16 fp32 from src, split to bf16 hi/lo, write swizzled to LDS row r.
// (o_gemm B-path pattern, proven rounds 5-7.)
static __device__ __forceinline__ void stage_split16(
    const float* __restrict__ src, u16* __restrict__ Lh, u16* __restrict__ Ll,
    int r, int hf, int ssw) {
  float tmp[16];
  *(float4*)&tmp[0] = *(const float4*)(src);
  *(float4*)&tmp[4] = *(const float4*)(src + 4);
  *(float4*)&tmp[8] = *(const float4*)(src + 8);
  *(float4*)&tmp[12] = *(const float4*)(src + 12);
  u16 hbuf[16], lbuf[16];
#pragma unroll
  for (int ii = 0; ii < 16; ++ii) split_bf16(tmp[ii], hbuf[ii], lbuf[ii]);
#pragma unroll
  for (int j = 0; j < 2; ++j) {
    int bs = ((2 * hf + j) ^ ssw) * 8;
    bf16x8 hv, lv;
#pragma unroll
    for (int q2 = 0; q2 < 8; ++q2) {
      hv[q2] = (short)hbuf[j * 8 + q2];
      lv[q2] = (short)lbuf[j * 8 + q2];
    }
    *(bf16x8*)&Lh[r * 32 + bs] = hv;
    *(bf16x8*)&Ll[r * 32 + bs] = lv;
  }
}

// ---------------- QKV projection GEMM (split-bf16 MFMA, 3-term) ----------
// Reads fp32 x,w directly; splits during staging. Epilogue: Q,K bf16 hi/lo
// [bh][s][64]; V transposed single fp16 [bh][d][s].
__global__ __launch_bounds__(256) void qkv_gemm_mfma(
    const float* __restrict__ x, const float* __restrict__ wg,
    const float* __restrict__ bias, u16* __restrict__ Qhi,
    u16* __restrict__ Qlo, u16* __restrict__ Khi, u16* __restrict__ Klo,
    u16* __restrict__ Vt) {
  __shared__ __align__(16) u16 Ah[4096], Al[4096], Bh[4096], Bl[4096];
  const int tid = threadIdx.x;
  const int w = tid >> 6, lane = tid & 63;
  const int m = lane & 15, quad = lane >> 4;
  const int wm = w >> 1, wn = w & 1;
  const int m0 = blockIdx.x * 128, n0 = blockIdx.y * 128;
  const int sa = (quad ^ ((m >> 1) & 3)) * 8;  // fragment-read swizzle
  const int rS = tid >> 1, hf = tid & 1;
  const int sS = (rS >> 1) & 3;

  f32x4 acc[4][4];
  const f32x4 vzero = {0.f, 0.f, 0.f, 0.f};
#pragma unroll
  for (int mt = 0; mt < 4; ++mt)
#pragma unroll
    for (int nt = 0; nt < 4; ++nt) acc[mt][nt] = vzero;

  for (int k0 = 0; k0 < DMODEL; k0 += 32) {
    stage_split16(x + (size_t)(m0 + rS) * DMODEL + k0 + hf * 16, Ah, Al, rS,
                  hf, sS);
    stage_split16(wg + (size_t)(n0 + rS) * DMODEL + k0 + hf * 16, Bh, Bl, rS,
                  hf, sS);
    __syncthreads();
    bf16x8 afh[4], afl[4], bfh[4], bfl[4];
#pragma unroll
    for (int t = 0; t < 4; ++t) {
      int ra = (wm * 64 + t * 16 + m) * 32 + sa;
      afh[t] = *(const bf16x8*)&Ah[ra];
      afl[t] = *(const bf16x8*)&Al[ra];
      int rb = (wn * 64 + t * 16 + m) * 32 + sa;
      bfh[t] = *(const bf16x8*)&Bh[rb];
      bfl[t] = *(const bf16x8*)&Bl[rb];
    }
#pragma unroll
    for (int mt = 0; mt < 4; ++mt)
#pragma unroll
      for (int nt = 0; nt < 4; ++nt) {
        acc[mt][nt] = MFMA(afh[mt], bfh[nt], acc[mt][nt]);
        acc[mt][nt] = MFMA(afh[mt], bfl[nt], acc[mt][nt]);
        acc[mt][nt] = MFMA(afl[mt], bfh[nt], acc[mt][nt]);
      }
    __syncthreads();
  }
  // epilogue: bias, split/convert, scatter
#pragma unroll
  for (int mt = 0; mt < 4; ++mt) {
#pragma unroll
    for (int rg = 0; rg < 4; ++rg) {
      int grow = m0 + wm * 64 + mt * 16 + quad * 4 + rg;
      int bb = grow >> 11, s = grow & (S_LEN - 1);
#pragma unroll
      for (int nt = 0; nt < 4; ++nt) {
        int e = n0 + wn * 64 + nt * 16 + m;
        float val = acc[mt][nt][rg] + bias[e];
        int h = e / 192;
        int r = e - h * 192;
        int d = r & 63;
        int bh = bb * NH + h;
        if (r < 64) {
          u16 hi, lo;
          split_bf16(val, hi, lo);
          int off = (bh * S_LEN + s) * HDIM + d;
          Qhi[off] = hi; Qlo[off] = lo;
        } else if (r < 128) {
          u16 hi, lo;
          split_bf16(val, hi, lo);
          int off = (bh * S_LEN + s) * HDIM + d;
          Khi[off] = hi; Klo[off] = lo;
        } else {
          Vt[(bh * HDIM + d) * S_LEN + s] = f2h_bits(val);
        }
      }
    }
  }
}

// ---------------- Output projection GEMM (split-bf16 MFMA, 3-term) --------
__global__ __launch_bounds__(256) void o_gemm_mfma(
    const u16* __restrict__ valh, const u16* __restrict__ vall,
    const float* __restrict__ ow, const float* __restrict__ bias,
    float* __restrict__ out) {
  __shared__ __align__(16) u16 Ah[4096], Al[4096], Bh[4096], Bl[4096];
  const int tid = threadIdx.x;
  const int w = tid >> 6, lane = tid & 63;
  const int m = lane & 15, quad = lane >> 4;
  const int wm = w >> 1, wn = w & 1;
  const int m0 = blockIdx.x * 128, n0 = blockIdx.y * 128;
  const int rl = lane >> 2, bp = lane & 3;
  const int sst = (rl >> 1) & 3;
  const int sa = (quad ^ ((m >> 1) & 3)) * 8;
  const int rB = tid >> 1, hf = tid & 1;
  const int sB = (rB >> 1) & 3;

  f32x4 acc[4][4];
  const f32x4 vzero = {0.f, 0.f, 0.f, 0.f};
#pragma unroll
  for (int mt = 0; mt < 4; ++mt)
#pragma unroll
    for (int nt = 0; nt < 4; ++nt) acc[mt][nt] = vzero;

  for (int k0 = 0; k0 < DMODEL; k0 += 32) {
#pragma unroll
    for (int i = 0; i < 2; ++i) {
      int cc = w * 2 + i;
      int row = cc * 16 + rl;
      int gofs = k0 + ((bp ^ sst) << 3);
      async_ld16(&Ah[cc * 512], valh + (size_t)(m0 + row) * DMODEL + gofs);
      async_ld16(&Al[cc * 512], vall + (size_t)(m0 + row) * DMODEL + gofs);
    }
    stage_split16(ow + (size_t)(n0 + rB) * DMODEL + k0 + hf * 16, Bh, Bl, rB,
                  hf, sB);
    __syncthreads();
    bf16x8 afh[4], afl[4], bfh[4], bfl[4];
#pragma unroll
    for (int t = 0; t < 4; ++t) {
      int ra = (wm * 64 + t * 16 + m) * 32 + sa;
      afh[t] = *(const bf16x8*)&Ah[ra];
      afl[t] = *(const bf16x8*)&Al[ra];
      int rb = (wn * 64 + t * 16 + m) * 32 + sa;
      bfh[t] = *(const bf16x8*)&Bh[rb];
      bfl[t] = *(const bf16x8*)&Bl[rb];
    }
#pragma unroll
    for (int mt = 0; mt < 4; ++mt)
#pragma unroll
      for (int nt = 0; nt < 4; ++nt) {
        acc[mt][nt] = MFMA(afh[mt], bfh[nt], acc[mt][nt]);
        acc[mt][nt] = MFMA(afh[mt], bfl[nt], acc[mt][nt]);
        acc[mt][nt] = MFMA(afl[mt], bfh[nt], acc[mt][nt]);
      }
    __syncthreads();
  }
#pragma unroll
  for (int mt = 0; mt < 4; ++mt) {
#pragma unroll
    for (int rg = 0; rg < 4; ++rg) {
      int grow = m0 + wm * 64 + mt * 16 + quad * 4 + rg;
#pragma unroll
      for (int nt = 0; nt < 4; ++nt) {
        int e = n0 + wn * 64 + nt * 16 + m;
        out[(size_t)grow * DMODEL + e] = acc[mt][nt][rg] + bias[e];
      }
    }
  }
}

// Per-(b,h) column sums of V (fp16 transposed), for all-pruned fallback.
__global__ __launch_bounds__(256) void vsum_kernel(const u16* __restrict__ Vt,
                                                   float* __restrict__ vsum) {
  const int bh = blockIdx.x;
  const int tid = threadIdx.x;
  const int d = tid >> 2, part = tid & 3;
  int base = (bh * HDIM + d) * S_LEN + part * 512;
  float s = 0.f;
  for (int k = 0; k < 512; k += 8) {
    f16x8 vv = *(const f16x8*)(Vt + base + k);
#pragma unroll
    for (int j = 0; j < 8; ++j) s += (float)vv[j];
  }
  __shared__ float red[64][4];
  red[d][part] = s;
  __syncthreads();
  if (part == 0)
    vsum[bh * HDIM + d] = red[d][0] + red[d][1] + red[d][2] + red[d][3];
}

// Fused two-pass pruned attention. QK^T: split-bf16 3-term (error below the
// projection's own 3-term noise). PV: fp16 P,V via f16 MFMA; Z2 uses the
// fp16-rounded p. No max subtraction (logits bounded). exp via exp2 with
// folded scale. 56KB LDS; pass 2 runs ONE barrier per tile (K and V both
// double-buffered; P round-trip is same-wave, lgkmcnt only).
__global__ __launch_bounds__(256) void attn_mfma_kernel(
    const u16* __restrict__ Qhi, const u16* __restrict__ Qlo,
    const u16* __restrict__ Khi, const u16* __restrict__ Klo,
    const u16* __restrict__ Vt, const float* __restrict__ thr,
    const float* __restrict__ vsum, u16* __restrict__ valh,
    u16* __restrict__ vall) {
  const int blk = blockIdx.x;
  const int qt = blk & 31, bh = blk >> 5;
  const int h = bh & (NH - 1), bb = bh >> 4;
  const int tid = threadIdx.x;
  const int w = tid >> 6, lane = tid & 63;
  const int m = lane & 15, quad = lane >> 4;
  const int rsub = lane >> 3;                    // 0..7: row within 8-row chunk
  const int bsw = (lane & 7) ^ rsub;             // swizzled 16B-block index

  // 56KB LDS: K bf16 hi/lo dbuf (32K), V fp16 dbuf (16K), P fp16 (8K)
  __shared__ __align__(16) u16 Kh_s[2][4096];
  __shared__ __align__(16) u16 Kl_s[2][4096];
  __shared__ __align__(16) u16 Vs_s[2][4096];
  __shared__ __align__(16) u16 Pf_s[4][16][64];

  // persistent Q fragments (A-operand: A[m=lane&15][k=quad*8+j])
  const int qoff = (bh * S_LEN + qt * 64 + w * 16 + m) * HDIM + quad * 8;
  const bf16x8 aQh0 = *(const bf16x8*)(Qhi + qoff);
  const bf16x8 aQh1 = *(const bf16x8*)(Qhi + qoff + 32);
  const bf16x8 aQl0 = *(const bf16x8*)(Qlo + qoff);
  const bf16x8 aQl1 = *(const bf16x8*)(Qlo + qoff + 32);

  const u16* KhT = Khi + bh * S_LEN * HDIM;
  const u16* KlT = Klo + bh * S_LEN * HDIM;
  const u16* VtT = Vt + bh * HDIM * S_LEN;
  const float th = thr[h];

  // swizzled read offsets (within a 64-short row; depends only on lane)
  const int s0 = (quad ^ (m & 7)) * 8;
  const int s1 = ((4 + quad) ^ (m & 7)) * 8;

  float Zr[4], Z2r[4], tzr[4];
#pragma unroll
  for (int r = 0; r < 4; ++r) { Zr[r] = 0.f; Z2r[r] = 0.f; }

  const f32x4 vzero = {0.f, 0.f, 0.f, 0.f};

  // stage helpers: each wave stages chunks {2w, 2w+1} of each tile
#define STAGE_K(bufi, t)                                                     \
  {                                                                          \
    const u16* gh = KhT + (t) * 64 * 64;                                     \
    const u16* gl = KlT + (t) * 64 * 64;                                     \
    _Pragma("unroll") for (int i = 0; i < 2; ++i) {                          \
      int c = w * 2 + i;                                                     \
      int row = c * 8 + rsub;                                                \
      async_ld16(&Kh_s[bufi][c * 512], gh + row * 64 + bsw * 8);             \
      async_ld16(&Kl_s[bufi][c * 512], gl + row * 64 + bsw * 8);             \
    }                                                                        \
  }
#define STAGE_V(bufi, t)                                                     \
  {                                                                          \
    _Pragma("unroll") for (int i = 0; i < 2; ++i) {                          \
      int c = w * 2 + i;                                                     \
      int row = c * 8 + rsub;                                                \
      async_ld16(&Vs_s[bufi][c * 512], VtT + row * 2048 + (t) * 64 + bsw * 8); \
    }                                                                        \
  }

// 3-term split-bf16 QK^T into acc[4] (K from LDS buffer `cur`)
#define QK_TILE(cur)                                                         \
  _Pragma("unroll") for (int nt = 0; nt < 4; ++nt) {                         \
    const int ro = (nt * 16 + m) * 64;                                       \
    bf16x8 kh0 = *(const bf16x8*)&Kh_s[cur][ro + s0];                        \
    bf16x8 kh1 = *(const bf16x8*)&Kh_s[cur][ro + s1];                        \
    bf16x8 kl0 = *(const bf16x8*)&Kl_s[cur][ro + s0];                        \
    bf16x8 kl1 = *(const bf16x8*)&Kl_s[cur][ro + s1];                        \
    acc[nt] = MFMA(aQh0, kh0, acc[nt]);                                      \
    acc[nt] = MFMA(aQh1, kh1, acc[nt]);                                      \
    acc[nt] = MFMA(aQh0, kl0, acc[nt]);                                      \
    acc[nt] = MFMA(aQh1, kl1, acc[nt]);                                      \
    acc[nt] = MFMA(aQl0, kh0, acc[nt]);                                      \
    acc[nt] = MFMA(aQl1, kh1, acc[nt]);                                      \
  }

  // ------- pass 1: denominator Z (lane-local, no cross-lane per tile) -----
  STAGE_K(0, 0);
  __syncthreads();
  for (int t = 0; t < 32; ++t) {
    const int cur = t & 1;
    if (t < 31) STAGE_K(cur ^ 1, t + 1);
    f32x4 acc[4];
#pragma unroll
    for (int nt = 0; nt < 4; ++nt) acc[nt] = vzero;
    QK_TILE(cur);
#pragma unroll
    for (int r = 0; r < 4; ++r) {
      Zr[r] += __builtin_exp2f(acc[0][r] * KC) + __builtin_exp2f(acc[1][r] * KC) +
               __builtin_exp2f(acc[2][r] * KC) + __builtin_exp2f(acc[3][r] * KC);
    }
    __syncthreads();
  }
#pragma unroll
  for (int r = 0; r < 4; ++r) tzr[r] = th * qredsum(Zr[r]);

  // ------- pass 2: masked (pruned) softmax + PV, 1 barrier per tile -------
  f32x4 oacc[4];
#pragma unroll
  for (int nt = 0; nt < 4; ++nt) oacc[nt] = vzero;

  STAGE_K(0, 0);
  STAGE_V(0, 0);
  __syncthreads();
  for (int t = 0; t < 32; ++t) {
    const int cur = t & 1;
    if (t < 31) {
      STAGE_K(cur ^ 1, t + 1);
      STAGE_V(cur ^ 1, t + 1);
    }
    f32x4 acc[4];
#pragma unroll
    for (int nt = 0; nt < 4; ++nt) acc[nt] = vzero;
    QK_TILE(cur);
    // prune + stage P (fp16) into xor-swizzled per-wave LDS (same-wave use)
#pragma unroll
    for (int r = 0; r < 4; ++r) {
      int row = quad * 4 + r;
      float psum = 0.f;
#pragma unroll
      for (int nt = 0; nt < 4; ++nt) {
        float pu = __builtin_exp2f(acc[nt][r] * KC);
        float p = (pu > tzr[r]) ? pu : 0.f;
        _Float16 p16 = (_Float16)p;
        psum += (float)p16;  // denominator sees the same rounding as PV
        int col = nt * 16 + m;
        int cs = (((col >> 3) ^ (row & 7)) << 3) | (col & 7);
        Pf_s[w][row][cs] = *(u16*)&p16;
      }
      Z2r[r] += psum;  // lane-local partial; reduced once in epilogue
    }
    // P A-fragments from swizzled LDS (same-wave; compiler emits lgkmcnt)
    f16x8 aP0 = *(const f16x8*)&Pf_s[w][m][s0];
    f16x8 aP1 = *(const f16x8*)&Pf_s[w][m][s1];
    // PV: B-operand from LDS-staged transposed fp16 V (B[n=d][k=key])
#pragma unroll
    for (int nt = 0; nt < 4; ++nt) {
      const int ro = (nt * 16 + m) * 64;
      f16x8 vv0 = *(const f16x8*)&Vs_s[cur][ro + s0];
      f16x8 vv1 = *(const f16x8*)&Vs_s[cur][ro + s1];
      oacc[nt] = MFMA16(aP0, vv0, oacc[nt]);
      oacc[nt] = MFMA16(aP1, vv1, oacc[nt]);
    }
    __syncthreads();  // waves done with cur bufs; t+1 staging drained
  }

  // ---------------- epilogue: normalize (or uniform fallback), write -------
#pragma unroll
  for (int r = 0; r < 4; ++r) {
    float z2 = qredsum(Z2r[r]);
    float invz = (z2 > 0.f) ? (1.f / z2) : 0.f;
    int srow = qt * 64 + w * 16 + quad * 4 + r;
#pragma unroll
    for (int nt = 0; nt < 4; ++nt) {
      float vs = vsum[bh * HDIM + nt * 16 + m];
      float o = (z2 > 0.f) ? (oacc[nt][r] * invz) : (vs * (1.0f / S_LEN));
      int idx = (bb * S_LEN + srow) * DMODEL + h * HDIM + nt * 16 + m;
      u16 hi, lo;
      split_bf16(o, hi, lo);
      valh[idx] = hi;
      vall[idx] = lo;
    }
  }
}

extern "C" void kernel_launch(void* const* d_in, const int* in_sizes, int n_in,
                              void* d_out, int out_size, void* d_ws, size_t ws_size,
                              hipStream_t stream) {
  const float* x = (const float*)d_in[0];
  const float* thresholds = (const float*)d_in[1];
  const float* qkv_w = (const float*)d_in[2];
  const float* qkv_b = (const float*)d_in[3];
  const float* o_w = (const float*)d_in[4];
  const float* o_b = (const float*)d_in[5];

  const size_t NBH = (size_t)BATCH * NH * S_LEN * HDIM;  // 4194304
  u16* base = (u16*)d_ws;
  u16* Qhi = base;
  u16* Qlo = base + NBH;
  u16* Khi = base + 2 * NBH;
  u16* Klo = base + 3 * NBH;
  u16* Vt = base + 4 * NBH;                // fp16 single, transposed
  float* vsum = (float*)(base + 5 * NBH);  // 2048 floats
  u16* valh = (u16*)(vsum + 2048);
  u16* vall = valh + NBH;

  dim3 g1(32, 24);
  qkv_gemm_mfma<<<g1, 256, 0, stream>>>(x, qkv_w, qkv_b, Qhi, Qlo, Khi, Klo,
                                        Vt);
  vsum_kernel<<<BATCH * NH, 256, 0, stream>>>(Vt, vsum);
  attn_mfma_kernel<<<BATCH * NH * (S_LEN / 64), 256, 0, stream>>>(
      Qhi, Qlo, Khi, Klo, Vt, thresholds, vsum, valh, vall);
  dim3 g3(32, 8);
  o_gemm_mfma<<<g3, 256, 0, stream>>>(valh, vall, o_w, o_b, (float*)d_out);
}

// Round 9
// 437.170 us; speedup vs baseline: 1.1334x; 1.1334x over previous
//
#include <hip/hip_runtime.h>
#include <math.h>

#define BATCH 2
#define S_LEN 2048
#define DMODEL 1024
#define NH 16
#define HDIM 64
#define SCALE 0.125f
// SCALE * log2(e): exp(l*SCALE) == exp2(l*KC)
#define KC 0.18033688011112042f

typedef short bf16x8 __attribute__((ext_vector_type(8)));
typedef _Float16 f16x8 __attribute__((ext_vector_type(8)));
typedef float f32x4 __attribute__((ext_vector_type(4)));
typedef unsigned short u16;
typedef unsigned short u16x4 __attribute__((ext_vector_type(4)));
#define MFMA(a, b, c) __builtin_amdgcn_mfma_f32_16x16x32_bf16(a, b, c, 0, 0, 0)
#define MFMA16(a, b, c) __builtin_amdgcn_mfma_f32_16x16x32_f16(a, b, c, 0, 0, 0)

static __device__ __forceinline__ float bf2f(u16 u) {
  return __uint_as_float(((unsigned int)u) << 16);
}
static __device__ __forceinline__ u16 f2h_bits(float a) {
  _Float16 h = (_Float16)a;
  return *(u16*)&h;
}

// round-to-nearest-even split: a ~= hi + lo, both bf16
static __device__ __forceinline__ void split_bf16(float a, u16& hi, u16& lo) {
  unsigned int u = __float_as_uint(a);
  unsigned int r = (u + 0x7fffu + ((u >> 16) & 1u)) >> 16;
  hi = (u16)r;
  float res = a - __uint_as_float(r << 16);
  unsigned int u2 = __float_as_uint(res);
  lo = (u16)((u2 + 0x7fffu + ((u2 >> 16) & 1u)) >> 16);
}

static __device__ __forceinline__ float qredsum(float v) {
#pragma unroll
  for (int off = 8; off >= 1; off >>= 1) v += __shfl_xor(v, off, 16);
  return v;
}

// async global->LDS, 16B per lane; LDS dest = wave-uniform base + lane*16
static __device__ __forceinline__ void async_ld16(u16* lds, const u16* g) {
  __builtin_amdgcn_global_load_lds(
      (const __attribute__((address_space(1))) void*)(const void*)g,
      (__attribute__((address_space(3))) void*)(void*)lds, 16, 0, 0);
}

// ---------------- elementwise fp32 -> bf16 hi/lo split ----------------
__global__ __launch_bounds__(256) void split_pair_kernel(
    const float* __restrict__ in, u16* __restrict__ hi, u16* __restrict__ lo,
    int n) {
  int idx = (blockIdx.x * 256 + threadIdx.x) * 4;
  if (idx >= n) return;
  float4 v = *(const float4*)(in + idx);
  u16 h0, h1, h2, h3, l0, l1, l2, l3;
  split_bf16(v.x, h0, l0);
  split_bf16(v.y, h1, l1);
  split_bf16(v.z, h2, l2);
  split_bf16(v.w, h3, l3);
  u16x4 h = {h0, h1, h2, h3};
  u16x4 l = {l0, l1, l2, l3};
  *(u16x4*)(hi + idx) = h;
  *(u16x4*)(lo + idx) = l;
}

// ---------------- QKV projection GEMM (split-bf16 MFMA, 3-term) ----------
// Epilogue: Q,K bf16 hi/lo [bh][s][64]; V transposed single fp16 [bh][d][s].
__global__ __launch_bounds__(256) void qkv_gemm_mfma(
    const u16* __restrict__ xh, const u16* __restrict__ xl,
    const u16* __restrict__ wh, const u16* __restrict__ wl,
    const float* __restrict__ bias, u16* __restrict__ Qhi,
    u16* __restrict__ Qlo, u16* __restrict__ Khi, u16* __restrict__ Klo,
    u16* __restrict__ Vt) {
  __shared__ __align__(16) u16 Ah[4096], Al[4096], Bh[4096], Bl[4096];
  const int tid = threadIdx.x;
  const int w = tid >> 6, lane = tid & 63;
  const int m = lane & 15, quad = lane >> 4;
  const int wm = w >> 1, wn = w & 1;
  const int m0 = blockIdx.x * 128, n0 = blockIdx.y * 128;
  const int rl = lane >> 2, bp = lane & 3;
  const int sst = (rl >> 1) & 3;                 // staging swizzle
  const int sa = (quad ^ ((m >> 1) & 3)) * 8;    // fragment-read swizzle

  f32x4 acc[4][4];
  const f32x4 vzero = {0.f, 0.f, 0.f, 0.f};
#pragma unroll
  for (int mt = 0; mt < 4; ++mt)
#pragma unroll
    for (int nt = 0; nt < 4; ++nt) acc[mt][nt] = vzero;

  for (int k0 = 0; k0 < DMODEL; k0 += 32) {
#pragma unroll
    for (int i = 0; i < 2; ++i) {
      int cc = w * 2 + i;
      int row = cc * 16 + rl;
      int gofs = k0 + ((bp ^ sst) << 3);
      async_ld16(&Ah[cc * 512], xh + (size_t)(m0 + row) * DMODEL + gofs);
      async_ld16(&Al[cc * 512], xl + (size_t)(m0 + row) * DMODEL + gofs);
      async_ld16(&Bh[cc * 512], wh + (size_t)(n0 + row) * DMODEL + gofs);
      async_ld16(&Bl[cc * 512], wl + (size_t)(n0 + row) * DMODEL + gofs);
    }
    __syncthreads();
    bf16x8 afh[4], afl[4], bfh[4], bfl[4];
#pragma unroll
    for (int t = 0; t < 4; ++t) {
      int ra = (wm * 64 + t * 16 + m) * 32 + sa;
      afh[t] = *(const bf16x8*)&Ah[ra];
      afl[t] = *(const bf16x8*)&Al[ra];
      int rb = (wn * 64 + t * 16 + m) * 32 + sa;
      bfh[t] = *(const bf16x8*)&Bh[rb];
      bfl[t] = *(const bf16x8*)&Bl[rb];
    }
#pragma unroll
    for (int mt = 0; mt < 4; ++mt)
#pragma unroll
      for (int nt = 0; nt < 4; ++nt) {
        acc[mt][nt] = MFMA(afh[mt], bfh[nt], acc[mt][nt]);
        acc[mt][nt] = MFMA(afh[mt], bfl[nt], acc[mt][nt]);
        acc[mt][nt] = MFMA(afl[mt], bfh[nt], acc[mt][nt]);
      }
    __syncthreads();
  }
  // epilogue: bias, split/convert, scatter
#pragma unroll
  for (int mt = 0; mt < 4; ++mt) {
#pragma unroll
    for (int rg = 0; rg < 4; ++rg) {
      int grow = m0 + wm * 64 + mt * 16 + quad * 4 + rg;
      int bb = grow >> 11, s = grow & (S_LEN - 1);
#pragma unroll
      for (int nt = 0; nt < 4; ++nt) {
        int e = n0 + wn * 64 + nt * 16 + m;
        float val = acc[mt][nt][rg] + bias[e];
        int h = e / 192;
        int r = e - h * 192;
        int d = r & 63;
        int bh = bb * NH + h;
        if (r < 64) {
          u16 hi, lo;
          split_bf16(val, hi, lo);
          int off = (bh * S_LEN + s) * HDIM + d;
          Qhi[off] = hi; Qlo[off] = lo;
        } else if (r < 128) {
          u16 hi, lo;
          split_bf16(val, hi, lo);
          int off = (bh * S_LEN + s) * HDIM + d;
          Khi[off] = hi; Klo[off] = lo;
        } else {
          Vt[(bh * HDIM + d) * S_LEN + s] = f2h_bits(val);
        }
      }
    }
  }
}

// ---------------- Output projection GEMM (split-bf16 MFMA, 3-term) --------
__global__ __launch_bounds__(256) void o_gemm_mfma(
    const u16* __restrict__ valh, const u16* __restrict__ vall,
    const float* __restrict__ ow, const float* __restrict__ bias,
    float* __restrict__ out) {
  __shared__ __align__(16) u16 Ah[4096], Al[4096], Bh[4096], Bl[4096];
  const int tid = threadIdx.x;
  const int w = tid >> 6, lane = tid & 63;
  const int m = lane & 15, quad = lane >> 4;
  const int wm = w >> 1, wn = w & 1;
  const int m0 = blockIdx.x * 128, n0 = blockIdx.y * 128;
  const int rl = lane >> 2, bp = lane & 3;
  const int sst = (rl >> 1) & 3;
  const int sa = (quad ^ ((m >> 1) & 3)) * 8;
  const int rB = tid >> 1, hf = tid & 1;
  const int sB = (rB >> 1) & 3;

  f32x4 acc[4][4];
  const f32x4 vzero = {0.f, 0.f, 0.f, 0.f};
#pragma unroll
  for (int mt = 0; mt < 4; ++mt)
#pragma unroll
    for (int nt = 0; nt < 4; ++nt) acc[mt][nt] = vzero;

  for (int k0 = 0; k0 < DMODEL; k0 += 32) {
#pragma unroll
    for (int i = 0; i < 2; ++i) {
      int cc = w * 2 + i;
      int row = cc * 16 + rl;
      int gofs = k0 + ((bp ^ sst) << 3);
      async_ld16(&Ah[cc * 512], valh + (size_t)(m0 + row) * DMODEL + gofs);
      async_ld16(&Al[cc * 512], vall + (size_t)(m0 + row) * DMODEL + gofs);
    }
    {
      const float* src = ow + (size_t)(n0 + rB) * DMODEL + k0 + hf * 16;
      float tmp[16];
      *(float4*)&tmp[0] = *(const float4*)(src);
      *(float4*)&tmp[4] = *(const float4*)(src + 4);
      *(float4*)&tmp[8] = *(const float4*)(src + 8);
      *(float4*)&tmp[12] = *(const float4*)(src + 12);
      u16 hbuf[16], lbuf[16];
#pragma unroll
      for (int ii = 0; ii < 16; ++ii) split_bf16(tmp[ii], hbuf[ii], lbuf[ii]);
#pragma unroll
      for (int j = 0; j < 2; ++j) {
        int bs = ((2 * hf + j) ^ sB) * 8;
        bf16x8 hv, lv;
#pragma unroll
        for (int q2 = 0; q2 < 8; ++q2) {
          hv[q2] = (short)hbuf[j * 8 + q2];
          lv[q2] = (short)lbuf[j * 8 + q2];
        }
        *(bf16x8*)&Bh[rB * 32 + bs] = hv;
        *(bf16x8*)&Bl[rB * 32 + bs] = lv;
      }
    }
    __syncthreads();
    bf16x8 afh[4], afl[4], bfh[4], bfl[4];
#pragma unroll
    for (int t = 0; t < 4; ++t) {
      int ra = (wm * 64 + t * 16 + m) * 32 + sa;
      afh[t] = *(const bf16x8*)&Ah[ra];
      afl[t] = *(const bf16x8*)&Al[ra];
      int rb = (wn * 64 + t * 16 + m) * 32 + sa;
      bfh[t] = *(const bf16x8*)&Bh[rb];
      bfl[t] = *(const bf16x8*)&Bl[rb];
    }
#pragma unroll
    for (int mt = 0; mt < 4; ++mt)
#pragma unroll
      for (int nt = 0; nt < 4; ++nt) {
        acc[mt][nt] = MFMA(afh[mt], bfh[nt], acc[mt][nt]);
        acc[mt][nt] = MFMA(afh[mt], bfl[nt], acc[mt][nt]);
        acc[mt][nt] = MFMA(afl[mt], bfh[nt], acc[mt][nt]);
      }
    __syncthreads();
  }
#pragma unroll
  for (int mt = 0; mt < 4; ++mt) {
#pragma unroll
    for (int rg = 0; rg < 4; ++rg) {
      int grow = m0 + wm * 64 + mt * 16 + quad * 4 + rg;
#pragma unroll
      for (int nt = 0; nt < 4; ++nt) {
        int e = n0 + wn * 64 + nt * 16 + m;
        out[(size_t)grow * DMODEL + e] = acc[mt][nt][rg] + bias[e];
      }
    }
  }
}

// Per-(b,h) column sums of V (fp16 transposed), for all-pruned fallback.
__global__ __launch_bounds__(256) void vsum_kernel(const u16* __restrict__ Vt,
                                                   float* __restrict__ vsum) {
  const int bh = blockIdx.x;
  const int tid = threadIdx.x;
  const int d = tid >> 2, part = tid & 3;
  int base = (bh * HDIM + d) * S_LEN + part * 512;
  float s = 0.f;
  for (int k = 0; k < 512; k += 8) {
    f16x8 vv = *(const f16x8*)(Vt + base + k);
#pragma unroll
    for (int j = 0; j < 8; ++j) s += (float)vv[j];
  }
  __shared__ float red[64][4];
  red[d][part] = s;
  __syncthreads();
  if (part == 0)
    vsum[bh * HDIM + d] = red[d][0] + red[d][1] + red[d][2] + red[d][3];
}

// Fused two-pass pruned attention. QK^T: split-bf16 3-term. PV: fp16 P,V via
// f16 MFMA; Z2 uses the fp16-rounded p. No max subtraction (logits bounded).
// exp via exp2 with folded scale. 48KB LDS -> 3 blocks/CU (proven round 7).
__global__ __launch_bounds__(256) void attn_mfma_kernel(
    const u16* __restrict__ Qhi, const u16* __restrict__ Qlo,
    const u16* __restrict__ Khi, const u16* __restrict__ Klo,
    const u16* __restrict__ Vt, const float* __restrict__ thr,
    const float* __restrict__ vsum, u16* __restrict__ valh,
    u16* __restrict__ vall) {
  const int blk = blockIdx.x;
  const int qt = blk & 31, bh = blk >> 5;
  const int h = bh & (NH - 1), bb = bh >> 4;
  const int tid = threadIdx.x;
  const int w = tid >> 6, lane = tid & 63;
  const int m = lane & 15, quad = lane >> 4;
  const int rsub = lane >> 3;                    // 0..7: row within 8-row chunk
  const int bsw = (lane & 7) ^ rsub;             // swizzled 16B-block index

  // 48KB LDS: K bf16 hi/lo double-buffered (32K), V fp16 (8K), P fp16 (8K)
  __shared__ __align__(16) u16 Kh_s[2][4096];
  __shared__ __align__(16) u16 Kl_s[2][4096];
  __shared__ __align__(16) u16 Vs_s[4096];
  __shared__ __align__(16) u16 Pf_s[4][16][64];

  // persistent Q fragments (A-operand: A[m=lane&15][k=quad*8+j])
  const int qoff = (bh * S_LEN + qt * 64 + w * 16 + m) * HDIM + quad * 8;
  const bf16x8 aQh0 = *(const bf16x8*)(Qhi + qoff);
  const bf16x8 aQh1 = *(const bf16x8*)(Qhi + qoff + 32);
  const bf16x8 aQl0 = *(const bf16x8*)(Qlo + qoff);
  const bf16x8 aQl1 = *(const bf16x8*)(Qlo + qoff + 32);

  const u16* KhT = Khi + bh * S_LEN * HDIM;
  const u16* KlT = Klo + bh * S_LEN * HDIM;
  const u16* VtT = Vt + bh * HDIM * S_LEN;
  const float th = thr[h];

  // swizzled read offsets (within a 64-short row; depends only on lane)
  const int s0 = (quad ^ (m & 7)) * 8;
  const int s1 = ((4 + quad) ^ (m & 7)) * 8;

  float Zr[4], Z2r[4], tzr[4];
#pragma unroll
  for (int r = 0; r < 4; ++r) { Zr[r] = 0.f; Z2r[r] = 0.f; }

  const f32x4 vzero = {0.f, 0.f, 0.f, 0.f};

  // stage helpers: each wave stages chunks {2w, 2w+1} of each tile
#define STAGE_K(bufi, t)                                                     \
  {                                                                          \
    const u16* gh = KhT + (t) * 64 * 64;                                     \
    const u16* gl = KlT + (t) * 64 * 64;                                     \
    _Pragma("unroll") for (int i = 0; i < 2; ++i) {                          \
      int c = w * 2 + i;                                                     \
      int row = c * 8 + rsub;                                                \
      async_ld16(&Kh_s[bufi][c * 512], gh + row * 64 + bsw * 8);             \
      async_ld16(&Kl_s[bufi][c * 512], gl + row * 64 + bsw * 8);             \
    }                                                                        \
  }
#define STAGE_V(t)                                                           \
  {                                                                          \
    _Pragma("unroll") for (int i = 0; i < 2; ++i) {                          \
      int c = w * 2 + i;                                                     \
      int row = c * 8 + rsub;                                                \
      async_ld16(&Vs_s[c * 512], VtT + row * 2048 + (t) * 64 + bsw * 8);     \
    }                                                                        \
  }

// 3-term split-bf16 QK^T into acc[4] (K from LDS buffer `cur`)
#define QK_TILE(cur)                                                         \
  _Pragma("unroll") for (int nt = 0; nt < 4; ++nt) {                         \
    const int ro = (nt * 16 + m) * 64;                                       \
    bf16x8 kh0 = *(const bf16x8*)&Kh_s[cur][ro + s0];                        \
    bf16x8 kh1 = *(const bf16x8*)&Kh_s[cur][ro + s1];                        \
    bf16x8 kl0 = *(const bf16x8*)&Kl_s[cur][ro + s0];                        \
    bf16x8 kl1 = *(const bf16x8*)&Kl_s[cur][ro + s1];                        \
    acc[nt] = MFMA(aQh0, kh0, acc[nt]);                                      \
    acc[nt] = MFMA(aQh1, kh1, acc[nt]);                                      \
    acc[nt] = MFMA(aQh0, kl0, acc[nt]);                                      \
    acc[nt] = MFMA(aQh1, kl1, acc[nt]);                                      \
    acc[nt] = MFMA(aQl0, kh0, acc[nt]);                                      \
    acc[nt] = MFMA(aQl1, kh1, acc[nt]);                                      \
  }

  // ------- pass 1: denominator Z (lane-local, no cross-lane per tile) -----
  STAGE_K(0, 0);
  __syncthreads();
  for (int t = 0; t < 32; ++t) {
    const int cur = t & 1;
    if (t < 31) STAGE_K(cur ^ 1, t + 1);
    f32x4 acc[4];
#pragma unroll
    for (int nt = 0; nt < 4; ++nt) acc[nt] = vzero;
    QK_TILE(cur);
#pragma unroll
    for (int r = 0; r < 4; ++r) {
      Zr[r] += __builtin_exp2f(acc[0][r] * KC) + __builtin_exp2f(acc[1][r] * KC) +
               __builtin_exp2f(acc[2][r] * KC) + __builtin_exp2f(acc[3][r] * KC);
    }
    __syncthreads();
  }
#pragma unroll
  for (int r = 0; r < 4; ++r) tzr[r] = th * qredsum(Zr[r]);

  // ---------------- pass 2: masked (pruned) softmax + PV ----------------
  f32x4 oacc[4];
#pragma unroll
  for (int nt = 0; nt < 4; ++nt) oacc[nt] = vzero;

  STAGE_K(0, 0);
  __syncthreads();
  for (int t = 0; t < 32; ++t) {
    const int cur = t & 1;
    STAGE_V(t);
    if (t < 31) STAGE_K(cur ^ 1, t + 1);
    f32x4 acc[4];
#pragma unroll
    for (int nt = 0; nt < 4; ++nt) acc[nt] = vzero;
    QK_TILE(cur);
    // prune + stage P (fp16) into xor-swizzled per-wave LDS
#pragma unroll
    for (int r = 0; r < 4; ++r) {
      int row = quad * 4 + r;
      float psum = 0.f;
#pragma unroll
      for (int nt = 0; nt < 4; ++nt) {
        float pu = __builtin_exp2f(acc[nt][r] * KC);
        float p = (pu > tzr[r]) ? pu : 0.f;
        _Float16 p16 = (_Float16)p;
        psum += (float)p16;  // denominator sees the same rounding as PV
        int col = nt * 16 + m;
        int cs = (((col >> 3) ^ (row & 7)) << 3) | (col & 7);
        Pf_s[w][row][cs] = *(u16*)&p16;
      }
      Z2r[r] += psum;  // lane-local partial; reduced once in epilogue
    }
    __syncthreads();  // V(t) (and K(t+1)) staged; P visible (per-wave anyway)
    // P A-fragments from swizzled LDS (conflict-free b128)
    f16x8 aP0 = *(const f16x8*)&Pf_s[w][m][s0];
    f16x8 aP1 = *(const f16x8*)&Pf_s[w][m][s1];
    // PV: B-operand from LDS-staged transposed fp16 V (B[n=d][k=key])
#pragma unroll
    for (int nt = 0; nt < 4; ++nt) {
      const int ro = (nt * 16 + m) * 64;
      f16x8 vv0 = *(const f16x8*)&Vs_s[ro + s0];
      f16x8 vv1 = *(const f16x8*)&Vs_s[ro + s1];
      oacc[nt] = MFMA16(aP0, vv0, oacc[nt]);
      oacc[nt] = MFMA16(aP1, vv1, oacc[nt]);
    }
    __syncthreads();  // all waves done with V buf / K[cur] before restage
  }

  // ---------------- epilogue: normalize (or uniform fallback), write -------
#pragma unroll
  for (int r = 0; r < 4; ++r) {
    float z2 = qredsum(Z2r[r]);
    float invz = (z2 > 0.f) ? (1.f / z2) : 0.f;
    int srow = qt * 64 + w * 16 + quad * 4 + r;
#pragma unroll
    for (int nt = 0; nt < 4; ++nt) {
      float vs = vsum[bh * HDIM + nt * 16 + m];
      float o = (z2 > 0.f) ? (oacc[nt][r] * invz) : (vs * (1.0f / S_LEN));
      int idx = (bb * S_LEN + srow) * DMODEL + h * HDIM + nt * 16 + m;
      u16 hi, lo;
      split_bf16(o, hi, lo);
      valh[idx] = hi;
      vall[idx] = lo;
    }
  }
}

extern "C" void kernel_launch(void* const* d_in, const int* in_sizes, int n_in,
                              void* d_out, int out_size, void* d_ws, size_t ws_size,
                              hipStream_t stream) {
  const float* x = (const float*)d_in[0];
  const float* thresholds = (const float*)d_in[1];
  const float* qkv_w = (const float*)d_in[2];
  const float* qkv_b = (const float*)d_in[3];
  const float* o_w = (const float*)d_in[4];
  const float* o_b = (const float*)d_in[5];

  const size_t NBH = (size_t)BATCH * NH * S_LEN * HDIM;  // 4194304
  u16* base = (u16*)d_ws;
  u16* Qhi = base;
  u16* Qlo = base + NBH;
  u16* Khi = base + 2 * NBH;
  u16* Klo = base + 3 * NBH;
  u16* Vt = base + 4 * NBH;                // fp16 single, transposed
  float* vsum = (float*)(base + 5 * NBH);  // 2048 floats
  u16* R1 = (u16*)(vsum + 2048);           // 8M u16: x splits, then values
  u16* xh = R1;
  u16* xl = R1 + NBH;
  u16* valh = R1;       // aliases xh/xl after qkv_gemm is done with x
  u16* vall = R1 + NBH;
  // qkv_w splits live in d_out (dead by the time o_gemm writes the output)
  u16* wh = (u16*)d_out;
  u16* wl = wh + (size_t)3 * DMODEL * DMODEL;

  split_pair_kernel<<<4096, 256, 0, stream>>>(x, xh, xl, (int)NBH);
  split_pair_kernel<<<3072, 256, 0, stream>>>(qkv_w, wh, wl, 3 * DMODEL * DMODEL);
  dim3 g1(32, 24);
  qkv_gemm_mfma<<<g1, 256, 0, stream>>>(xh, xl, wh, wl, qkv_b, Qhi, Qlo, Khi,
                                        Klo, Vt);
  vsum_kernel<<<BATCH * NH, 256, 0, stream>>>(Vt, vsum);
  attn_mfma_kernel<<<BATCH * NH * (S_LEN / 64), 256, 0, stream>>>(
      Qhi, Qlo, Khi, Klo, Vt, thresholds, vsum, valh, vall);
  dim3 g3(32, 8);
  o_gemm_mfma<<<g3, 256, 0, stream>>>(valh, vall, o_w, o_b, (float*)d_out);
}

// Round 10
// 436.767 us; speedup vs baseline: 1.1345x; 1.0009x over previous
//
#include <hip/hip_runtime.h>
#include <math.h>

#define BATCH 2
#define S_LEN 2048
#define DMODEL 1024
#define NH 16
#define HDIM 64
#define SCALE 0.125f
// SCALE * log2(e): exp(l*SCALE) == exp2(l*KC)
#define KC 0.18033688011112042f

typedef short bf16x8 __attribute__((ext_vector_type(8)));
typedef _Float16 f16x8 __attribute__((ext_vector_type(8)));
typedef float f32x4 __attribute__((ext_vector_type(4)));
typedef unsigned short u16;
typedef unsigned short u16x4 __attribute__((ext_vector_type(4)));
#define MFMA(a, b, c) __builtin_amdgcn_mfma_f32_16x16x32_bf16(a, b, c, 0, 0, 0)
#define MFMA16(a, b, c) __builtin_amdgcn_mfma_f32_16x16x32_f16(a, b, c, 0, 0, 0)

static __device__ __forceinline__ float bf2f(u16 u) {
  return __uint_as_float(((unsigned int)u) << 16);
}
static __device__ __forceinline__ u16 f2h_bits(float a) {
  _Float16 h = (_Float16)a;
  return *(u16*)&h;
}

// round-to-nearest-even split: a ~= hi + lo, both bf16
static __device__ __forceinline__ void split_bf16(float a, u16& hi, u16& lo) {
  unsigned int u = __float_as_uint(a);
  unsigned int r = (u + 0x7fffu + ((u >> 16) & 1u)) >> 16;
  hi = (u16)r;
  float res = a - __uint_as_float(r << 16);
  unsigned int u2 = __float_as_uint(res);
  lo = (u16)((u2 + 0x7fffu + ((u2 >> 16) & 1u)) >> 16);
}

static __device__ __forceinline__ float qredsum(float v) {
#pragma unroll
  for (int off = 8; off >= 1; off >>= 1) v += __shfl_xor(v, off, 16);
  return v;
}

// async global->LDS, 16B per lane; LDS dest = wave-uniform base + lane*16
static __device__ __forceinline__ void async_ld16(u16* lds, const u16* g) {
  __builtin_amdgcn_global_load_lds(
      (const __attribute__((address_space(1))) void*)(const void*)g,
      (__attribute__((address_space(3))) void*)(void*)lds, 16, 0, 0);
}

static __device__ __forceinline__ void do_split4(const float* __restrict__ in,
                                                 u16* __restrict__ hi,
                                                 u16* __restrict__ lo, int idx) {
  float4 v = *(const float4*)(in + idx);
  u16 h0, h1, h2, h3, l0, l1, l2, l3;
  split_bf16(v.x, h0, l0);
  split_bf16(v.y, h1, l1);
  split_bf16(v.z, h2, l2);
  split_bf16(v.w, h3, l3);
  u16x4 h = {h0, h1, h2, h3};
  u16x4 l = {l0, l1, l2, l3};
  *(u16x4*)(hi + idx) = h;
  *(u16x4*)(lo + idx) = l;
}

// One kernel splits both x and qkv_w (fp32 -> bf16 hi/lo)
__global__ __launch_bounds__(256) void split_two_kernel(
    const float* __restrict__ a, u16* __restrict__ ah, u16* __restrict__ al,
    int na, const float* __restrict__ b, u16* __restrict__ bh,
    u16* __restrict__ bl, int nb) {
  int idx = (blockIdx.x * 256 + threadIdx.x) * 4;
  if (idx < na) {
    do_split4(a, ah, al, idx);
  } else {
    int j = idx - na;
    if (j < nb) do_split4(b, bh, bl, j);
  }
}

// ---------------- QKV projection GEMM (split-bf16 MFMA, 3-term) ----------
// Epilogue: Q,K bf16 hi/lo [bh][s][64]; V transposed single fp16 [bh][d][s].
__global__ __launch_bounds__(256) void qkv_gemm_mfma(
    const u16* __restrict__ xh, const u16* __restrict__ xl,
    const u16* __restrict__ wh, const u16* __restrict__ wl,
    const float* __restrict__ bias, u16* __restrict__ Qhi,
    u16* __restrict__ Qlo, u16* __restrict__ Khi, u16* __restrict__ Klo,
    u16* __restrict__ Vt) {
  __shared__ __align__(16) u16 Ah[4096], Al[4096], Bh[4096], Bl[4096];
  const int tid = threadIdx.x;
  const int w = tid >> 6, lane = tid & 63;
  const int m = lane & 15, quad = lane >> 4;
  const int wm = w >> 1, wn = w & 1;
  const int m0 = blockIdx.x * 128, n0 = blockIdx.y * 128;
  const int rl = lane >> 2, bp = lane & 3;
  const int sst = (rl >> 1) & 3;                 // staging swizzle
  const int sa = (quad ^ ((m >> 1) & 3)) * 8;    // fragment-read swizzle

  f32x4 acc[4][4];
  const f32x4 vzero = {0.f, 0.f, 0.f, 0.f};
#pragma unroll
  for (int mt = 0; mt < 4; ++mt)
#pragma unroll
    for (int nt = 0; nt < 4; ++nt) acc[mt][nt] = vzero;

  for (int k0 = 0; k0 < DMODEL; k0 += 32) {
#pragma unroll
    for (int i = 0; i < 2; ++i) {
      int cc = w * 2 + i;
      int row = cc * 16 + rl;
      int gofs = k0 + ((bp ^ sst) << 3);
      async_ld16(&Ah[cc * 512], xh + (size_t)(m0 + row) * DMODEL + gofs);
      async_ld16(&Al[cc * 512], xl + (size_t)(m0 + row) * DMODEL + gofs);
      async_ld16(&Bh[cc * 512], wh + (size_t)(n0 + row) * DMODEL + gofs);
      async_ld16(&Bl[cc * 512], wl + (size_t)(n0 + row) * DMODEL + gofs);
    }
    __syncthreads();
    bf16x8 afh[4], afl[4], bfh[4], bfl[4];
#pragma unroll
    for (int t = 0; t < 4; ++t) {
      int ra = (wm * 64 + t * 16 + m) * 32 + sa;
      afh[t] = *(const bf16x8*)&Ah[ra];
      afl[t] = *(const bf16x8*)&Al[ra];
      int rb = (wn * 64 + t * 16 + m) * 32 + sa;
      bfh[t] = *(const bf16x8*)&Bh[rb];
      bfl[t] = *(const bf16x8*)&Bl[rb];
    }
#pragma unroll
    for (int mt = 0; mt < 4; ++mt)
#pragma unroll
      for (int nt = 0; nt < 4; ++nt) {
        acc[mt][nt] = MFMA(afh[mt], bfh[nt], acc[mt][nt]);
        acc[mt][nt] = MFMA(afh[mt], bfl[nt], acc[mt][nt]);
        acc[mt][nt] = MFMA(afl[mt], bfh[nt], acc[mt][nt]);
      }
    __syncthreads();
  }
  // epilogue: bias, split/convert, scatter
#pragma unroll
  for (int mt = 0; mt < 4; ++mt) {
#pragma unroll
    for (int rg = 0; rg < 4; ++rg) {
      int grow = m0 + wm * 64 + mt * 16 + quad * 4 + rg;
      int bb = grow >> 11, s = grow & (S_LEN - 1);
#pragma unroll
      for (int nt = 0; nt < 4; ++nt) {
        int e = n0 + wn * 64 + nt * 16 + m;
        float val = acc[mt][nt][rg] + bias[e];
        int h = e / 192;
        int r = e - h * 192;
        int d = r & 63;
        int bh = bb * NH + h;
        if (r < 64) {
          u16 hi, lo;
          split_bf16(val, hi, lo);
          int off = (bh * S_LEN + s) * HDIM + d;
          Qhi[off] = hi; Qlo[off] = lo;
        } else if (r < 128) {
          u16 hi, lo;
          split_bf16(val, hi, lo);
          int off = (bh * S_LEN + s) * HDIM + d;
          Khi[off] = hi; Klo[off] = lo;
        } else {
          Vt[(bh * HDIM + d) * S_LEN + s] = f2h_bits(val);
        }
      }
    }
  }
}

// ---------------- Output projection GEMM (split-bf16 MFMA, 3-term) --------
__global__ __launch_bounds__(256) void o_gemm_mfma(
    const u16* __restrict__ valh, const u16* __restrict__ vall,
    const float* __restrict__ ow, const float* __restrict__ bias,
    float* __restrict__ out) {
  __shared__ __align__(16) u16 Ah[4096], Al[4096], Bh[4096], Bl[4096];
  const int tid = threadIdx.x;
  const int w = tid >> 6, lane = tid & 63;
  const int m = lane & 15, quad = lane >> 4;
  const int wm = w >> 1, wn = w & 1;
  const int m0 = blockIdx.x * 128, n0 = blockIdx.y * 128;
  const int rl = lane >> 2, bp = lane & 3;
  const int sst = (rl >> 1) & 3;
  const int sa = (quad ^ ((m >> 1) & 3)) * 8;
  const int rB = tid >> 1, hf = tid & 1;
  const int sB = (rB >> 1) & 3;

  f32x4 acc[4][4];
  const f32x4 vzero = {0.f, 0.f, 0.f, 0.f};
#pragma unroll
  for (int mt = 0; mt < 4; ++mt)
#pragma unroll
    for (int nt = 0; nt < 4; ++nt) acc[mt][nt] = vzero;

  for (int k0 = 0; k0 < DMODEL; k0 += 32) {
#pragma unroll
    for (int i = 0; i < 2; ++i) {
      int cc = w * 2 + i;
      int row = cc * 16 + rl;
      int gofs = k0 + ((bp ^ sst) << 3);
      async_ld16(&Ah[cc * 512], valh + (size_t)(m0 + row) * DMODEL + gofs);
      async_ld16(&Al[cc * 512], vall + (size_t)(m0 + row) * DMODEL + gofs);
    }
    {
      const float* src = ow + (size_t)(n0 + rB) * DMODEL + k0 + hf * 16;
      float tmp[16];
      *(float4*)&tmp[0] = *(const float4*)(src);
      *(float4*)&tmp[4] = *(const float4*)(src + 4);
      *(float4*)&tmp[8] = *(const float4*)(src + 8);
      *(float4*)&tmp[12] = *(const float4*)(src + 12);
      u16 hbuf[16], lbuf[16];
#pragma unroll
      for (int ii = 0; ii < 16; ++ii) split_bf16(tmp[ii], hbuf[ii], lbuf[ii]);
#pragma unroll
      for (int j = 0; j < 2; ++j) {
        int bs = ((2 * hf + j) ^ sB) * 8;
        bf16x8 hv, lv;
#pragma unroll
        for (int q2 = 0; q2 < 8; ++q2) {
          hv[q2] = (short)hbuf[j * 8 + q2];
          lv[q2] = (short)lbuf[j * 8 + q2];
        }
        *(bf16x8*)&Bh[rB * 32 + bs] = hv;
        *(bf16x8*)&Bl[rB * 32 + bs] = lv;
      }
    }
    __syncthreads();
    bf16x8 afh[4], afl[4], bfh[4], bfl[4];
#pragma unroll
    for (int t = 0; t < 4; ++t) {
      int ra = (wm * 64 + t * 16 + m) * 32 + sa;
      afh[t] = *(const bf16x8*)&Ah[ra];
      afl[t] = *(const bf16x8*)&Al[ra];
      int rb = (wn * 64 + t * 16 + m) * 32 + sa;
      bfh[t] = *(const bf16x8*)&Bh[rb];
      bfl[t] = *(const bf16x8*)&Bl[rb];
    }
#pragma unroll
    for (int mt = 0; mt < 4; ++mt)
#pragma unroll
      for (int nt = 0; nt < 4; ++nt) {
        acc[mt][nt] = MFMA(afh[mt], bfh[nt], acc[mt][nt]);
        acc[mt][nt] = MFMA(afh[mt], bfl[nt], acc[mt][nt]);
        acc[mt][nt] = MFMA(afl[mt], bfh[nt], acc[mt][nt]);
      }
    __syncthreads();
  }
#pragma unroll
  for (int mt = 0; mt < 4; ++mt) {
#pragma unroll
    for (int rg = 0; rg < 4; ++rg) {
      int grow = m0 + wm * 64 + mt * 16 + quad * 4 + rg;
#pragma unroll
      for (int nt = 0; nt < 4; ++nt) {
        int e = n0 + wn * 64 + nt * 16 + m;
        out[(size_t)grow * DMODEL + e] = acc[mt][nt][rg] + bias[e];
      }
    }
  }
}

// Per-(b,h) column sums of V (fp16 transposed), for all-pruned fallback.
__global__ __launch_bounds__(256) void vsum_kernel(const u16* __restrict__ Vt,
                                                   float* __restrict__ vsum) {
  const int bh = blockIdx.x;
  const int tid = threadIdx.x;
  const int d = tid >> 2, part = tid & 3;
  int base = (bh * HDIM + d) * S_LEN + part * 512;
  float s = 0.f;
  for (int k = 0; k < 512; k += 8) {
    f16x8 vv = *(const f16x8*)(Vt + base + k);
#pragma unroll
    for (int j = 0; j < 8; ++j) s += (float)vv[j];
  }
  __shared__ float red[64][4];
  red[d][part] = s;
  __syncthreads();
  if (part == 0)
    vsum[bh * HDIM + d] = red[d][0] + red[d][1] + red[d][2] + red[d][3];
}

// Fused two-pass pruned attention. QK^T: split-bf16 3-term. PV: fp16 P,V via
// f16 MFMA; Z2 uses the fp16-rounded p. No max subtraction (logits bounded).
// 40KB LDS (Kh dbuf 16K, Kl single 8K, V 8K, P 8K) -> 4 blocks/CU.
// Both passes: stage Kl(t)[+V(t)] + prefetch Kh(t+1); Kh-MFMAs; barrier;
// Kl-MFMAs; softmax/PV; barrier.
__global__ __launch_bounds__(256) void attn_mfma_kernel(
    const u16* __restrict__ Qhi, const u16* __restrict__ Qlo,
    const u16* __restrict__ Khi, const u16* __restrict__ Klo,
    const u16* __restrict__ Vt, const float* __restrict__ thr,
    const float* __restrict__ vsum, u16* __restrict__ valh,
    u16* __restrict__ vall) {
  const int blk = blockIdx.x;
  const int qt = blk & 31, bh = blk >> 5;
  const int h = bh & (NH - 1), bb = bh >> 4;
  const int tid = threadIdx.x;
  const int w = tid >> 6, lane = tid & 63;
  const int m = lane & 15, quad = lane >> 4;
  const int rsub = lane >> 3;                    // 0..7: row within 8-row chunk
  const int bsw = (lane & 7) ^ rsub;             // swizzled 16B-block index

  __shared__ __align__(16) u16 Kh_s[2][4096];
  __shared__ __align__(16) u16 Kl_s[4096];
  __shared__ __align__(16) u16 Vs_s[4096];
  __shared__ __align__(16) u16 Pf_s[4][16][64];

  // persistent Q fragments (A-operand: A[m=lane&15][k=quad*8+j])
  const int qoff = (bh * S_LEN + qt * 64 + w * 16 + m) * HDIM + quad * 8;
  const bf16x8 aQh0 = *(const bf16x8*)(Qhi + qoff);
  const bf16x8 aQh1 = *(const bf16x8*)(Qhi + qoff + 32);
  const bf16x8 aQl0 = *(const bf16x8*)(Qlo + qoff);
  const bf16x8 aQl1 = *(const bf16x8*)(Qlo + qoff + 32);

  const u16* KhT = Khi + bh * S_LEN * HDIM;
  const u16* KlT = Klo + bh * S_LEN * HDIM;
  const u16* VtT = Vt + bh * HDIM * S_LEN;
  const float th = thr[h];

  // swizzled read offsets (within a 64-short row; depends only on lane)
  const int s0 = (quad ^ (m & 7)) * 8;
  const int s1 = ((4 + quad) ^ (m & 7)) * 8;

  float Zr[4], Z2r[4], tzr[4];
#pragma unroll
  for (int r = 0; r < 4; ++r) { Zr[r] = 0.f; Z2r[r] = 0.f; }

  const f32x4 vzero = {0.f, 0.f, 0.f, 0.f};

  // stage helpers: each wave stages chunks {2w, 2w+1} of each tile
#define STAGE_KH(bufi, t)                                                    \
  {                                                                          \
    const u16* gh = KhT + (t) * 64 * 64;                                     \
    _Pragma("unroll") for (int i = 0; i < 2; ++i) {                          \
      int c = w * 2 + i;                                                     \
      int row = c * 8 + rsub;                                                \
      async_ld16(&Kh_s[bufi][c * 512], gh + row * 64 + bsw * 8);             \
    }                                                                        \
  }
#define STAGE_KL(t)                                                          \
  {                                                                          \
    const u16* gl = KlT + (t) * 64 * 64;                                     \
    _Pragma("unroll") for (int i = 0; i < 2; ++i) {                          \
      int c = w * 2 + i;                                                     \
      int row = c * 8 + rsub;                                                \
      async_ld16(&Kl_s[c * 512], gl + row * 64 + bsw * 8);                   \
    }                                                                        \
  }
#define STAGE_V(t)                                                           \
  {                                                                          \
    _Pragma("unroll") for (int i = 0; i < 2; ++i) {                          \
      int c = w * 2 + i;                                                     \
      int row = c * 8 + rsub;                                                \
      async_ld16(&Vs_s[c * 512], VtT + row * 2048 + (t) * 64 + bsw * 8);     \
    }                                                                        \
  }

// Kh-dependent MFMAs (4 per nt): usable before Kl is ready
#define QK_HI(cur)                                                           \
  _Pragma("unroll") for (int nt = 0; nt < 4; ++nt) {                         \
    const int ro = (nt * 16 + m) * 64;                                       \
    bf16x8 kh0 = *(const bf16x8*)&Kh_s[cur][ro + s0];                        \
    bf16x8 kh1 = *(const bf16x8*)&Kh_s[cur][ro + s1];                        \
    acc[nt] = MFMA(aQh0, kh0, acc[nt]);                                      \
    acc[nt] = MFMA(aQh1, kh1, acc[nt]);                                      \
    acc[nt] = MFMA(aQl0, kh0, acc[nt]);                                      \
    acc[nt] = MFMA(aQl1, kh1, acc[nt]);                                      \
  }
// Kl-dependent MFMAs (2 per nt)
#define QK_LO()                                                              \
  _Pragma("unroll") for (int nt = 0; nt < 4; ++nt) {                         \
    const int ro = (nt * 16 + m) * 64;                                       \
    bf16x8 kl0 = *(const bf16x8*)&Kl_s[ro + s0];                             \
    bf16x8 kl1 = *(const bf16x8*)&Kl_s[ro + s1];                             \
    acc[nt] = MFMA(aQh0, kl0, acc[nt]);                                      \
    acc[nt] = MFMA(aQh1, kl1, acc[nt]);                                      \
  }

  // ------- pass 1: denominator Z (lane-local, no cross-lane per tile) -----
  STAGE_KH(0, 0);
  __syncthreads();
  for (int t = 0; t < 32; ++t) {
    const int cur = t & 1;
    STAGE_KL(t);
    if (t < 31) STAGE_KH(cur ^ 1, t + 1);
    f32x4 acc[4];
#pragma unroll
    for (int nt = 0; nt < 4; ++nt) acc[nt] = vzero;
    QK_HI(cur);
    __syncthreads();  // Kl(t) (and Kh(t+1)) staged
    QK_LO();
#pragma unroll
    for (int r = 0; r < 4; ++r) {
      Zr[r] += __builtin_exp2f(acc[0][r] * KC) + __builtin_exp2f(acc[1][r] * KC) +
               __builtin_exp2f(acc[2][r] * KC) + __builtin_exp2f(acc[3][r] * KC);
    }
    __syncthreads();  // all waves done with Kl / Kh[cur]
  }
#pragma unroll
  for (int r = 0; r < 4; ++r) tzr[r] = th * qredsum(Zr[r]);

  // ---------------- pass 2: masked (pruned) softmax + PV ----------------
  f32x4 oacc[4];
#pragma unroll
  for (int nt = 0; nt < 4; ++nt) oacc[nt] = vzero;

  STAGE_KH(0, 0);
  __syncthreads();
  for (int t = 0; t < 32; ++t) {
    const int cur = t & 1;
    STAGE_KL(t);
    STAGE_V(t);
    if (t < 31) STAGE_KH(cur ^ 1, t + 1);
    f32x4 acc[4];
#pragma unroll
    for (int nt = 0; nt < 4; ++nt) acc[nt] = vzero;
    QK_HI(cur);
    __syncthreads();  // Kl(t), V(t) (and Kh(t+1)) staged
    QK_LO();
    // prune + stage P (fp16) into xor-swizzled per-wave LDS (same-wave use)
#pragma unroll
    for (int r = 0; r < 4; ++r) {
      int row = quad * 4 + r;
      float psum = 0.f;
#pragma unroll
      for (int nt = 0; nt < 4; ++nt) {
        float pu = __builtin_exp2f(acc[nt][r] * KC);
        float p = (pu > tzr[r]) ? pu : 0.f;
        _Float16 p16 = (_Float16)p;
        psum += (float)p16;  // denominator sees the same rounding as PV
        int col = nt * 16 + m;
        int cs = (((col >> 3) ^ (row & 7)) << 3) | (col & 7);
        Pf_s[w][row][cs] = *(u16*)&p16;
      }
      Z2r[r] += psum;  // lane-local partial; reduced once in epilogue
    }
    // P A-fragments from swizzled LDS (same-wave; compiler emits lgkmcnt)
    f16x8 aP0 = *(const f16x8*)&Pf_s[w][m][s0];
    f16x8 aP1 = *(const f16x8*)&Pf_s[w][m][s1];
    // PV: B-operand from LDS-staged transposed fp16 V (B[n=d][k=key])
#pragma unroll
    for (int nt = 0; nt < 4; ++nt) {
      const int ro = (nt * 16 + m) * 64;
      f16x8 vv0 = *(const f16x8*)&Vs_s[ro + s0];
      f16x8 vv1 = *(const f16x8*)&Vs_s[ro + s1];
      oacc[nt] = MFMA16(aP0, vv0, oacc[nt]);
      oacc[nt] = MFMA16(aP1, vv1, oacc[nt]);
    }
    __syncthreads();  // all waves done with Kl / V / Kh[cur]
  }

  // ---------------- epilogue: normalize (or uniform fallback), write -------
#pragma unroll
  for (int r = 0; r < 4; ++r) {
    float z2 = qredsum(Z2r[r]);
    float invz = (z2 > 0.f) ? (1.f / z2) : 0.f;
    int srow = qt * 64 + w * 16 + quad * 4 + r;
#pragma unroll
    for (int nt = 0; nt < 4; ++nt) {
      float vs = vsum[bh * HDIM + nt * 16 + m];
      float o = (z2 > 0.f) ? (oacc[nt][r] * invz) : (vs * (1.0f / S_LEN));
      int idx = (bb * S_LEN + srow) * DMODEL + h * HDIM + nt * 16 + m;
      u16 hi, lo;
      split_bf16(o, hi, lo);
      valh[idx] = hi;
      vall[idx] = lo;
    }
  }
}

extern "C" void kernel_launch(void* const* d_in, const int* in_sizes, int n_in,
                              void* d_out, int out_size, void* d_ws, size_t ws_size,
                              hipStream_t stream) {
  const float* x = (const float*)d_in[0];
  const float* thresholds = (const float*)d_in[1];
  const float* qkv_w = (const float*)d_in[2];
  const float* qkv_b = (const float*)d_in[3];
  const float* o_w = (const float*)d_in[4];
  const float* o_b = (const float*)d_in[5];

  const size_t NBH = (size_t)BATCH * NH * S_LEN * HDIM;  // 4194304
  const int NW = 3 * DMODEL * DMODEL;                    // 3145728
  u16* base = (u16*)d_ws;
  u16* Qhi = base;
  u16* Qlo = base + NBH;
  u16* Khi = base + 2 * NBH;
  u16* Klo = base + 3 * NBH;
  u16* Vt = base + 4 * NBH;                // fp16 single, transposed
  float* vsum = (float*)(base + 5 * NBH);  // 2048 floats
  u16* R1 = (u16*)(vsum + 2048);           // 8M u16: x splits, then values
  u16* xh = R1;
  u16* xl = R1 + NBH;
  u16* valh = R1;       // aliases xh/xl after qkv_gemm is done with x
  u16* vall = R1 + NBH;
  // qkv_w splits live in d_out (dead by the time o_gemm writes the output)
  u16* wh = (u16*)d_out;
  u16* wl = wh + (size_t)NW;

  int ntot = ((int)NBH + NW) / 4;  // 4-elem units
  split_two_kernel<<<(ntot + 255) / 256, 256, 0, stream>>>(
      x, xh, xl, (int)NBH, qkv_w, wh, wl, NW);
  dim3 g1(32, 24);
  qkv_gemm_mfma<<<g1, 256, 0, stream>>>(xh, xl, wh, wl, qkv_b, Qhi, Qlo, Khi,
                                        Klo, Vt);
  vsum_kernel<<<BATCH * NH, 256, 0, stream>>>(Vt, vsum);
  attn_mfma_kernel<<<BATCH * NH * (S_LEN / 64), 256, 0, stream>>>(
      Qhi, Qlo, Khi, Klo, Vt, thresholds, vsum, valh, vall);
  dim3 g3(32, 8);
  o_gemm_mfma<<<g3, 256, 0, stream>>>(valh, vall, o_w, o_b, (float*)d_out);
}

// Round 11
// 430.361 us; speedup vs baseline: 1.1514x; 1.0149x over previous
//
#include <hip/hip_runtime.h>
#include <math.h>

#define BATCH 2
#define S_LEN 2048
#define DMODEL 1024
#define NH 16
#define HDIM 64
#define SCALE 0.125f
// SCALE * log2(e): exp(l*SCALE) == exp2(l*KC)
#define KC 0.18033688011112042f

typedef short bf16x8 __attribute__((ext_vector_type(8)));
typedef _Float16 f16x8 __attribute__((ext_vector_type(8)));
typedef float f32x4 __attribute__((ext_vector_type(4)));
typedef unsigned short u16;
typedef unsigned short u16x4 __attribute__((ext_vector_type(4)));
#define MFMA(a, b, c) __builtin_amdgcn_mfma_f32_16x16x32_bf16(a, b, c, 0, 0, 0)
#define MFMA16(a, b, c) __builtin_amdgcn_mfma_f32_16x16x32_f16(a, b, c, 0, 0, 0)

static __device__ __forceinline__ float bf2f(u16 u) {
  return __uint_as_float(((unsigned int)u) << 16);
}
static __device__ __forceinline__ u16 f2h_bits(float a) {
  _Float16 h = (_Float16)a;
  return *(u16*)&h;
}

// round-to-nearest-even split: a ~= hi + lo, both bf16
static __device__ __forceinline__ void split_bf16(float a, u16& hi, u16& lo) {
  unsigned int u = __float_as_uint(a);
  unsigned int r = (u + 0x7fffu + ((u >> 16) & 1u)) >> 16;
  hi = (u16)r;
  float res = a - __uint_as_float(r << 16);
  unsigned int u2 = __float_as_uint(res);
  lo = (u16)((u2 + 0x7fffu + ((u2 >> 16) & 1u)) >> 16);
}

static __device__ __forceinline__ float qredsum(float v) {
#pragma unroll
  for (int off = 8; off >= 1; off >>= 1) v += __shfl_xor(v, off, 16);
  return v;
}

// async global->LDS, 16B per lane; LDS dest = wave-uniform base + lane*16
static __device__ __forceinline__ void async_ld16(u16* lds, const u16* g) {
  __builtin_amdgcn_global_load_lds(
      (const __attribute__((address_space(1))) void*)(const void*)g,
      (__attribute__((address_space(3))) void*)(void*)lds, 16, 0, 0);
}

static __device__ __forceinline__ void do_split4(const float* __restrict__ in,
                                                 u16* __restrict__ hi,
                                                 u16* __restrict__ lo, int idx) {
  float4 v = *(const float4*)(in + idx);
  u16 h0, h1, h2, h3, l0, l1, l2, l3;
  split_bf16(v.x, h0, l0);
  split_bf16(v.y, h1, l1);
  split_bf16(v.z, h2, l2);
  split_bf16(v.w, h3, l3);
  u16x4 h = {h0, h1, h2, h3};
  u16x4 l = {l0, l1, l2, l3};
  *(u16x4*)(hi + idx) = h;
  *(u16x4*)(lo + idx) = l;
}

// One kernel splits both x and qkv_w (fp32 -> bf16 hi/lo)
__global__ __launch_bounds__(256) void split_two_kernel(
    const float* __restrict__ a, u16* __restrict__ ah, u16* __restrict__ al,
    int na, const float* __restrict__ b, u16* __restrict__ bh,
    u16* __restrict__ bl, int nb) {
  int idx = (blockIdx.x * 256 + threadIdx.x) * 4;
  if (idx < na) {
    do_split4(a, ah, al, idx);
  } else {
    int j = idx - na;
    if (j < nb) do_split4(b, bh, bl, j);
  }
}

// ---------------- QKV projection GEMM (split-bf16 MFMA, 3-term) ----------
// Epilogue: Q,K bf16 hi/lo [bh][s][64]; V transposed single fp16 [bh][d][s].
__global__ __launch_bounds__(256) void qkv_gemm_mfma(
    const u16* __restrict__ xh, const u16* __restrict__ xl,
    const u16* __restrict__ wh, const u16* __restrict__ wl,
    const float* __restrict__ bias, u16* __restrict__ Qhi,
    u16* __restrict__ Qlo, u16* __restrict__ Khi, u16* __restrict__ Klo,
    u16* __restrict__ Vt) {
  __shared__ __align__(16) u16 Ah[4096], Al[4096], Bh[4096], Bl[4096];
  const int tid = threadIdx.x;
  const int w = tid >> 6, lane = tid & 63;
  const int m = lane & 15, quad = lane >> 4;
  const int wm = w >> 1, wn = w & 1;
  const int m0 = blockIdx.x * 128, n0 = blockIdx.y * 128;
  const int rl = lane >> 2, bp = lane & 3;
  const int sst = (rl >> 1) & 3;                 // staging swizzle
  const int sa = (quad ^ ((m >> 1) & 3)) * 8;    // fragment-read swizzle

  f32x4 acc[4][4];
  const f32x4 vzero = {0.f, 0.f, 0.f, 0.f};
#pragma unroll
  for (int mt = 0; mt < 4; ++mt)
#pragma unroll
    for (int nt = 0; nt < 4; ++nt) acc[mt][nt] = vzero;

  for (int k0 = 0; k0 < DMODEL; k0 += 32) {
#pragma unroll
    for (int i = 0; i < 2; ++i) {
      int cc = w * 2 + i;
      int row = cc * 16 + rl;
      int gofs = k0 + ((bp ^ sst) << 3);
      async_ld16(&Ah[cc * 512], xh + (size_t)(m0 + row) * DMODEL + gofs);
      async_ld16(&Al[cc * 512], xl + (size_t)(m0 + row) * DMODEL + gofs);
      async_ld16(&Bh[cc * 512], wh + (size_t)(n0 + row) * DMODEL + gofs);
      async_ld16(&Bl[cc * 512], wl + (size_t)(n0 + row) * DMODEL + gofs);
    }
    __syncthreads();
    bf16x8 afh[4], afl[4], bfh[4], bfl[4];
#pragma unroll
    for (int t = 0; t < 4; ++t) {
      int ra = (wm * 64 + t * 16 + m) * 32 + sa;
      afh[t] = *(const bf16x8*)&Ah[ra];
      afl[t] = *(const bf16x8*)&Al[ra];
      int rb = (wn * 64 + t * 16 + m) * 32 + sa;
      bfh[t] = *(const bf16x8*)&Bh[rb];
      bfl[t] = *(const bf16x8*)&Bl[rb];
    }
#pragma unroll
    for (int mt = 0; mt < 4; ++mt)
#pragma unroll
      for (int nt = 0; nt < 4; ++nt) {
        acc[mt][nt] = MFMA(afh[mt], bfh[nt], acc[mt][nt]);
        acc[mt][nt] = MFMA(afh[mt], bfl[nt], acc[mt][nt]);
        acc[mt][nt] = MFMA(afl[mt], bfh[nt], acc[mt][nt]);
      }
    __syncthreads();
  }
  // epilogue: bias, split/convert, scatter
#pragma unroll
  for (int mt = 0; mt < 4; ++mt) {
#pragma unroll
    for (int rg = 0; rg < 4; ++rg) {
      int grow = m0 + wm * 64 + mt * 16 + quad * 4 + rg;
      int bb = grow >> 11, s = grow & (S_LEN - 1);
#pragma unroll
      for (int nt = 0; nt < 4; ++nt) {
        int e = n0 + wn * 64 + nt * 16 + m;
        float val = acc[mt][nt][rg] + bias[e];
        int h = e / 192;
        int r = e - h * 192;
        int d = r & 63;
        int bh = bb * NH + h;
        if (r < 64) {
          u16 hi, lo;
          split_bf16(val, hi, lo);
          int off = (bh * S_LEN + s) * HDIM + d;
          Qhi[off] = hi; Qlo[off] = lo;
        } else if (r < 128) {
          u16 hi, lo;
          split_bf16(val, hi, lo);
          int off = (bh * S_LEN + s) * HDIM + d;
          Khi[off] = hi; Klo[off] = lo;
        } else {
          Vt[(bh * HDIM + d) * S_LEN + s] = f2h_bits(val);
        }
      }
    }
  }
}

// ---------------- Output projection GEMM (split-bf16 MFMA, 3-term) --------
__global__ __launch_bounds__(256) void o_gemm_mfma(
    const u16* __restrict__ valh, const u16* __restrict__ vall,
    const float* __restrict__ ow, const float* __restrict__ bias,
    float* __restrict__ out) {
  __shared__ __align__(16) u16 Ah[4096], Al[4096], Bh[4096], Bl[4096];
  const int tid = threadIdx.x;
  const int w = tid >> 6, lane = tid & 63;
  const int m = lane & 15, quad = lane >> 4;
  const int wm = w >> 1, wn = w & 1;
  const int m0 = blockIdx.x * 128, n0 = blockIdx.y * 128;
  const int rl = lane >> 2, bp = lane & 3;
  const int sst = (rl >> 1) & 3;
  const int sa = (quad ^ ((m >> 1) & 3)) * 8;
  const int rB = tid >> 1, hf = tid & 1;
  const int sB = (rB >> 1) & 3;

  f32x4 acc[4][4];
  const f32x4 vzero = {0.f, 0.f, 0.f, 0.f};
#pragma unroll
  for (int mt = 0; mt < 4; ++mt)
#pragma unroll
    for (int nt = 0; nt < 4; ++nt) acc[mt][nt] = vzero;

  for (int k0 = 0; k0 < DMODEL; k0 += 32) {
#pragma unroll
    for (int i = 0; i < 2; ++i) {
      int cc = w * 2 + i;
      int row = cc * 16 + rl;
      int gofs = k0 + ((bp ^ sst) << 3);
      async_ld16(&Ah[cc * 512], valh + (size_t)(m0 + row) * DMODEL + gofs);
      async_ld16(&Al[cc * 512], vall + (size_t)(m0 + row) * DMODEL + gofs);
    }
    {
      const float* src = ow + (size_t)(n0 + rB) * DMODEL + k0 + hf * 16;
      float tmp[16];
      *(float4*)&tmp[0] = *(const float4*)(src);
      *(float4*)&tmp[4] = *(const float4*)(src + 4);
      *(float4*)&tmp[8] = *(const float4*)(src + 8);
      *(float4*)&tmp[12] = *(const float4*)(src + 12);
      u16 hbuf[16], lbuf[16];
#pragma unroll
      for (int ii = 0; ii < 16; ++ii) split_bf16(tmp[ii], hbuf[ii], lbuf[ii]);
#pragma unroll
      for (int j = 0; j < 2; ++j) {
        int bs = ((2 * hf + j) ^ sB) * 8;
        bf16x8 hv, lv;
#pragma unroll
        for (int q2 = 0; q2 < 8; ++q2) {
          hv[q2] = (short)hbuf[j * 8 + q2];
          lv[q2] = (short)lbuf[j * 8 + q2];
        }
        *(bf16x8*)&Bh[rB * 32 + bs] = hv;
        *(bf16x8*)&Bl[rB * 32 + bs] = lv;
      }
    }
    __syncthreads();
    bf16x8 afh[4], afl[4], bfh[4], bfl[4];
#pragma unroll
    for (int t = 0; t < 4; ++t) {
      int ra = (wm * 64 + t * 16 + m) * 32 + sa;
      afh[t] = *(const bf16x8*)&Ah[ra];
      afl[t] = *(const bf16x8*)&Al[ra];
      int rb = (wn * 64 + t * 16 + m) * 32 + sa;
      bfh[t] = *(const bf16x8*)&Bh[rb];
      bfl[t] = *(const bf16x8*)&Bl[rb];
    }
#pragma unroll
    for (int mt = 0; mt < 4; ++mt)
#pragma unroll
      for (int nt = 0; nt < 4; ++nt) {
        acc[mt][nt] = MFMA(afh[mt], bfh[nt], acc[mt][nt]);
        acc[mt][nt] = MFMA(afh[mt], bfl[nt], acc[mt][nt]);
        acc[mt][nt] = MFMA(afl[mt], bfh[nt], acc[mt][nt]);
      }
    __syncthreads();
  }
#pragma unroll
  for (int mt = 0; mt < 4; ++mt) {
#pragma unroll
    for (int rg = 0; rg < 4; ++rg) {
      int grow = m0 + wm * 64 + mt * 16 + quad * 4 + rg;
#pragma unroll
      for (int nt = 0; nt < 4; ++nt) {
        int e = n0 + wn * 64 + nt * 16 + m;
        out[(size_t)grow * DMODEL + e] = acc[mt][nt][rg] + bias[e];
      }
    }
  }
}

// Per-(b,h) column sums of V (fp16 transposed), for all-pruned fallback.
__global__ __launch_bounds__(256) void vsum_kernel(const u16* __restrict__ Vt,
                                                   float* __restrict__ vsum) {
  const int bh = blockIdx.x;
  const int tid = threadIdx.x;
  const int d = tid >> 2, part = tid & 3;
  int base = (bh * HDIM + d) * S_LEN + part * 512;
  float s = 0.f;
  for (int k = 0; k < 512; k += 8) {
    f16x8 vv = *(const f16x8*)(Vt + base + k);
#pragma unroll
    for (int j = 0; j < 8; ++j) s += (float)vv[j];
  }
  __shared__ float red[64][4];
  red[d][part] = s;
  __syncthreads();
  if (part == 0)
    vsum[bh * HDIM + d] = red[d][0] + red[d][1] + red[d][2] + red[d][3];
}

// Fused two-pass pruned attention. QK^T: split-bf16 3-term. PV: fp16 P,V via
// f16 MFMA; Z2 uses the fp16-rounded p. No max subtraction (logits bounded).
// 40KB LDS. XCD-aware block decode: bh = blk & 31 so all 32 Q-tile blocks of
// one (b,h) satisfy blk % 8 == bh % 8 -> same XCD under round-robin dispatch
// -> K/V stay L2-resident (per-XCD working set ~5MB vs 40MB before).
__global__ __launch_bounds__(256) void attn_mfma_kernel(
    const u16* __restrict__ Qhi, const u16* __restrict__ Qlo,
    const u16* __restrict__ Khi, const u16* __restrict__ Klo,
    const u16* __restrict__ Vt, const float* __restrict__ thr,
    const float* __restrict__ vsum, u16* __restrict__ valh,
    u16* __restrict__ vall) {
  const int blk = blockIdx.x;
  const int bh = blk & 31, qt = blk >> 5;   // XCD-grouping remap
  const int h = bh & (NH - 1), bb = bh >> 4;
  const int tid = threadIdx.x;
  const int w = tid >> 6, lane = tid & 63;
  const int m = lane & 15, quad = lane >> 4;
  const int rsub = lane >> 3;                    // 0..7: row within 8-row chunk
  const int bsw = (lane & 7) ^ rsub;             // swizzled 16B-block index

  __shared__ __align__(16) u16 Kh_s[2][4096];
  __shared__ __align__(16) u16 Kl_s[4096];
  __shared__ __align__(16) u16 Vs_s[4096];
  __shared__ __align__(16) u16 Pf_s[4][16][64];

  // persistent Q fragments (A-operand: A[m=lane&15][k=quad*8+j])
  const int qoff = (bh * S_LEN + qt * 64 + w * 16 + m) * HDIM + quad * 8;
  const bf16x8 aQh0 = *(const bf16x8*)(Qhi + qoff);
  const bf16x8 aQh1 = *(const bf16x8*)(Qhi + qoff + 32);
  const bf16x8 aQl0 = *(const bf16x8*)(Qlo + qoff);
  const bf16x8 aQl1 = *(const bf16x8*)(Qlo + qoff + 32);

  const u16* KhT = Khi + bh * S_LEN * HDIM;
  const u16* KlT = Klo + bh * S_LEN * HDIM;
  const u16* VtT = Vt + bh * HDIM * S_LEN;
  const float th = thr[h];

  // swizzled read offsets (within a 64-short row; depends only on lane)
  const int s0 = (quad ^ (m & 7)) * 8;
  const int s1 = ((4 + quad) ^ (m & 7)) * 8;

  float Zr[4], Z2r[4], tzr[4];
#pragma unroll
  for (int r = 0; r < 4; ++r) { Zr[r] = 0.f; Z2r[r] = 0.f; }

  const f32x4 vzero = {0.f, 0.f, 0.f, 0.f};

  // stage helpers: each wave stages chunks {2w, 2w+1} of each tile
#define STAGE_KH(bufi, t)                                                    \
  {                                                                          \
    const u16* gh = KhT + (t) * 64 * 64;                                     \
    _Pragma("unroll") for (int i = 0; i < 2; ++i) {                          \
      int c = w * 2 + i;                                                     \
      int row = c * 8 + rsub;                                                \
      async_ld16(&Kh_s[bufi][c * 512], gh + row * 64 + bsw * 8);             \
    }                                                                        \
  }
#define STAGE_KL(t)                                                          \
  {                                                                          \
    const u16* gl = KlT + (t) * 64 * 64;                                     \
    _Pragma("unroll") for (int i = 0; i < 2; ++i) {                          \
      int c = w * 2 + i;                                                     \
      int row = c * 8 + rsub;                                                \
      async_ld16(&Kl_s[c * 512], gl + row * 64 + bsw * 8);                   \
    }                                                                        \
  }
#define STAGE_V(t)                                                           \
  {                                                                          \
    _Pragma("unroll") for (int i = 0; i < 2; ++i) {                          \
      int c = w * 2 + i;                                                     \
      int row = c * 8 + rsub;                                                \
      async_ld16(&Vs_s[c * 512], VtT + row * 2048 + (t) * 64 + bsw * 8);     \
    }                                                                        \
  }

// Kh-dependent MFMAs (4 per nt): usable before Kl is ready
#define QK_HI(cur)                                                           \
  _Pragma("unroll") for (int nt = 0; nt < 4; ++nt) {                         \
    const int ro = (nt * 16 + m) * 64;                                       \
    bf16x8 kh0 = *(const bf16x8*)&Kh_s[cur][ro + s0];                        \
    bf16x8 kh1 = *(const bf16x8*)&Kh_s[cur][ro + s1];                        \
    acc[nt] = MFMA(aQh0, kh0, acc[nt]);                                      \
    acc[nt] = MFMA(aQh1, kh1, acc[nt]);                                      \
    acc[nt] = MFMA(aQl0, kh0, acc[nt]);                                      \
    acc[nt] = MFMA(aQl1, kh1, acc[nt]);                                      \
  }
// Kl-dependent MFMAs (2 per nt)
#define QK_LO()                                                              \
  _Pragma("unroll") for (int nt = 0; nt < 4; ++nt) {                         \
    const int ro = (nt * 16 + m) * 64;                                       \
    bf16x8 kl0 = *(const bf16x8*)&Kl_s[ro + s0];                             \
    bf16x8 kl1 = *(const bf16x8*)&Kl_s[ro + s1];                             \
    acc[nt] = MFMA(aQh0, kl0, acc[nt]);                                      \
    acc[nt] = MFMA(aQh1, kl1, acc[nt]);                                      \
  }

  // ------- pass 1: denominator Z (lane-local, no cross-lane per tile) -----
  STAGE_KH(0, 0);
  __syncthreads();
  for (int t = 0; t < 32; ++t) {
    const int cur = t & 1;
    STAGE_KL(t);
    if (t < 31) STAGE_KH(cur ^ 1, t + 1);
    f32x4 acc[4];
#pragma unroll
    for (int nt = 0; nt < 4; ++nt) acc[nt] = vzero;
    QK_HI(cur);
    __syncthreads();  // Kl(t) (and Kh(t+1)) staged
    QK_LO();
#pragma unroll
    for (int r = 0; r < 4; ++r) {
      Zr[r] += __builtin_exp2f(acc[0][r] * KC) + __builtin_exp2f(acc[1][r] * KC) +
               __builtin_exp2f(acc[2][r] * KC) + __builtin_exp2f(acc[3][r] * KC);
    }
    __syncthreads();  // all waves done with Kl / Kh[cur]
  }
#pragma unroll
  for (int r = 0; r < 4; ++r) tzr[r] = th * qredsum(Zr[r]);

  // ---------------- pass 2: masked (pruned) softmax + PV ----------------
  f32x4 oacc[4];
#pragma unroll
  for (int nt = 0; nt < 4; ++nt) oacc[nt] = vzero;

  STAGE_KH(0, 0);
  __syncthreads();
  for (int t = 0; t < 32; ++t) {
    const int cur = t & 1;
    STAGE_KL(t);
    STAGE_V(t);
    if (t < 31) STAGE_KH(cur ^ 1, t + 1);
    f32x4 acc[4];
#pragma unroll
    for (int nt = 0; nt < 4; ++nt) acc[nt] = vzero;
    QK_HI(cur);
    __syncthreads();  // Kl(t), V(t) (and Kh(t+1)) staged
    QK_LO();
    // prune + stage P (fp16) into xor-swizzled per-wave LDS (same-wave use)
#pragma unroll
    for (int r = 0; r < 4; ++r) {
      int row = quad * 4 + r;
      float psum = 0.f;
#pragma unroll
      for (int nt = 0; nt < 4; ++nt) {
        float pu = __builtin_exp2f(acc[nt][r] * KC);
        float p = (pu > tzr[r]) ? pu : 0.f;
        _Float16 p16 = (_Float16)p;
        psum += (float)p16;  // denominator sees the same rounding as PV
        int col = nt * 16 + m;
        int cs = (((col >> 3) ^ (row & 7)) << 3) | (col & 7);
        Pf_s[w][row][cs] = *(u16*)&p16;
      }
      Z2r[r] += psum;  // lane-local partial; reduced once in epilogue
    }
    // P A-fragments from swizzled LDS (same-wave; compiler emits lgkmcnt)
    f16x8 aP0 = *(const f16x8*)&Pf_s[w][m][s0];
    f16x8 aP1 = *(const f16x8*)&Pf_s[w][m][s1];
    // PV: B-operand from LDS-staged transposed fp16 V (B[n=d][k=key])
#pragma unroll
    for (int nt = 0; nt < 4; ++nt) {
      const int ro = (nt * 16 + m) * 64;
      f16x8 vv0 = *(const f16x8*)&Vs_s[ro + s0];
      f16x8 vv1 = *(const f16x8*)&Vs_s[ro + s1];
      oacc[nt] = MFMA16(aP0, vv0, oacc[nt]);
      oacc[nt] = MFMA16(aP1, vv1, oacc[nt]);
    }
    __syncthreads();  // all waves done with Kl / V / Kh[cur]
  }

  // ---------------- epilogue: normalize (or uniform fallback), write -------
#pragma unroll
  for (int r = 0; r < 4; ++r) {
    float z2 = qredsum(Z2r[r]);
    float invz = (z2 > 0.f) ? (1.f / z2) : 0.f;
    int srow = qt * 64 + w * 16 + quad * 4 + r;
#pragma unroll
    for (int nt = 0; nt < 4; ++nt) {
      float vs = vsum[bh * HDIM + nt * 16 + m];
      float o = (z2 > 0.f) ? (oacc[nt][r] * invz) : (vs * (1.0f / S_LEN));
      int idx = (bb * S_LEN + srow) * DMODEL + h * HDIM + nt * 16 + m;
      u16 hi, lo;
      split_bf16(o, hi, lo);
      valh[idx] = hi;
      vall[idx] = lo;
    }
  }
}

extern "C" void kernel_launch(void* const* d_in, const int* in_sizes, int n_in,
                              void* d_out, int out_size, void* d_ws, size_t ws_size,
                              hipStream_t stream) {
  const float* x = (const float*)d_in[0];
  const float* thresholds = (const float*)d_in[1];
  const float* qkv_w = (const float*)d_in[2];
  const float* qkv_b = (const float*)d_in[3];
  const float* o_w = (const float*)d_in[4];
  const float* o_b = (const float*)d_in[5];

  const size_t NBH = (size_t)BATCH * NH * S_LEN * HDIM;  // 4194304
  const int NW = 3 * DMODEL * DMODEL;                    // 3145728
  u16* base = (u16*)d_ws;
  u16* Qhi = base;
  u16* Qlo = base + NBH;
  u16* Khi = base + 2 * NBH;
  u16* Klo = base + 3 * NBH;
  u16* Vt = base + 4 * NBH;                // fp16 single, transposed
  float* vsum = (float*)(base + 5 * NBH);  // 2048 floats
  u16* R1 = (u16*)(vsum + 2048);           // 8M u16: x splits, then values
  u16* xh = R1;
  u16* xl = R1 + NBH;
  u16* valh = R1;       // aliases xh/xl after qkv_gemm is done with x
  u16* vall = R1 + NBH;
  // qkv_w splits live in d_out (dead by the time o_gemm writes the output)
  u16* wh = (u16*)d_out;
  u16* wl = wh + (size_t)NW;

  int ntot = ((int)NBH + NW) / 4;  // 4-elem units
  split_two_kernel<<<(ntot + 255) / 256, 256, 0, stream>>>(
      x, xh, xl, (int)NBH, qkv_w, wh, wl, NW);
  dim3 g1(32, 24);
  qkv_gemm_mfma<<<g1, 256, 0, stream>>>(xh, xl, wh, wl, qkv_b, Qhi, Qlo, Khi,
                                        Klo, Vt);
  vsum_kernel<<<BATCH * NH, 256, 0, stream>>>(Vt, vsum);
  attn_mfma_kernel<<<BATCH * NH * (S_LEN / 64), 256, 0, stream>>>(
      Qhi, Qlo, Khi, Klo, Vt, thresholds, vsum, valh, vall);
  dim3 g3(32, 8);
  o_gemm_mfma<<<g3, 256, 0, stream>>>(valh, vall, o_w, o_b, (float*)d_out);
}